// Round 6
// baseline (602.952 us; speedup 1.0000x reference)
//
#include <hip/hip_runtime.h>
#include <hip/hip_bf16.h>

// DownBlock: pool(mean over 7 down-neighbors) -> conv1(K=7, 32->64) -> BN+LReLU
//         -> conv2(K=7, 64->64) -> BN+LReLU
// B=16, C_IN=32, C=64, V_FINE=163842, V=40962, K=7.
// Biases b1/b2 are dead: BN's mean subtraction absorbs per-channel constants.
// Convs are gather-LATENCY-bound (R3->R4: time ~halved when waves/CU 8->16).
// R6: no weight-LDS (A-frags read from L2), 2 verts/wave, launch_bounds(256,5)
// => ~20-24 waves/CU.

#define B_SZ     16
#define CIN      32
#define CMID     64
#define VFINE    163842
#define VC       40962
#define KNB      7

typedef __attribute__((ext_vector_type(8))) short  short8;   // 8 x bf16 (as i16)
typedef __attribute__((ext_vector_type(4))) float  f32x4;
typedef __attribute__((ext_vector_type(4))) unsigned short u16x4;

__device__ inline float bf2f(unsigned short u) {
    return __builtin_bit_cast(float, (unsigned int)(((unsigned int)u) << 16));
}
__device__ inline unsigned short f2bf(float f) {
    __hip_bfloat16 h = __float2bfloat16(f);
    return __builtin_bit_cast(unsigned short, h);
}

// ---------------------------------------------------------------------------
// Prep: reorder W into per-lane MFMA A-fragments, bf16. Also zeroes stats.
// Fragment (chunk, otile): lane l, elem j ->  A[o = otile*16 + (l&15)][kk = (l>>4)*8 + j]
// conv1: chunk cc = k (7 chunks), c = kk.        W1[o][c*7+k]
// conv2: chunk cc = k*2 + ch (14), c = ch*32+kk. W2[o][c*7+k]
// ---------------------------------------------------------------------------
__global__ void prep_w(const float* __restrict__ w1, const float* __restrict__ w2,
                       unsigned short* __restrict__ w1f, unsigned short* __restrict__ w2f,
                       float* __restrict__ stats) {
    int tid = blockIdx.x * blockDim.x + threadIdx.x;
    int stride = gridDim.x * blockDim.x;
    if (blockIdx.x == 0 && threadIdx.x < 256) stats[threadIdx.x] = 0.f;
    const int total1 = 7 * 4 * 64 * 8;
    for (int idx = tid; idx < total1; idx += stride) {
        int j = idx & 7, l = (idx >> 3) & 63, t = (idx >> 9) & 3, cc = idx >> 11;
        int o = t * 16 + (l & 15);
        int kk = (l >> 4) * 8 + j;
        w1f[idx] = f2bf(w1[o * 224 + kk * 7 + cc]);
    }
    const int total2 = 14 * 4 * 64 * 8;
    for (int idx = tid; idx < total2; idx += stride) {
        int j = idx & 7, l = (idx >> 3) & 63, t = (idx >> 9) & 3, cc = idx >> 11;
        int o = t * 16 + (l & 15);
        int kk = (l >> 4) * 8 + j;
        int k = cc >> 1, ch = cc & 1;
        int c = ch * 32 + kk;
        w2f[idx] = f2bf(w2[o * 448 + c * 7 + k]);
    }
}

// ---------------------------------------------------------------------------
// Transpose x (512 rows x VFINE) f32 -> xt[v][512] bf16.
// 64-vertex tile, two 256-channel phases. LDS [64 verts][258 u16] (33KB).
// ---------------------------------------------------------------------------
__global__ __launch_bounds__(256) void transpose_x(const float* __restrict__ x,
                                                   unsigned short* __restrict__ xt, int vf) {
    __shared__ __align__(16) unsigned short lds[64 * 258];
    const int t = threadIdx.x;
    const int v0 = blockIdx.x * 64;
    const int j  = t & 15;        // load phase: vert group (4 verts)
    const int r0 = t >> 4;        // load phase: row base
    const int lane = t & 63;
    const int wid = t >> 6;

#pragma unroll
    for (int p = 0; p < 2; ++p) {
        if (p) __syncthreads();
#pragma unroll
        for (int it = 0; it < 16; ++it) {
            int r = r0 + it * 16;          // row within phase 0..255
            int row = p * 256 + r;
            int vg = v0 + 4 * j;
            f32x4 d = {0.f, 0.f, 0.f, 0.f};
            if (vg + 3 < vf) {
                d = *reinterpret_cast<const f32x4*>(x + (size_t)row * vf + vg);
            } else {
#pragma unroll
                for (int q = 0; q < 4; ++q)
                    if (vg + q < vf) d[q] = x[(size_t)row * vf + vg + q];
            }
#pragma unroll
            for (int q = 0; q < 4; ++q)
                lds[(4 * j + q) * 258 + r] = f2bf(d[q]);
        }
        __syncthreads();
#pragma unroll
        for (int i = 0; i < 16; ++i) {
            int v = wid * 16 + i;
            u16x4 o = *reinterpret_cast<const u16x4*>(lds + v * 258 + 4 * lane);
            if (v0 + v < vf)
                *reinterpret_cast<u16x4*>(xt + (size_t)(v0 + v) * 512 + p * 256 + 4 * lane) = o;
        }
    }
}

// ---------------------------------------------------------------------------
// Pool: xp[v][b][c] = mean_k xt[dn[v][k]][b][c]. One wave per coarse vertex.
// ---------------------------------------------------------------------------
__global__ __launch_bounds__(256) void pool_k(const unsigned short* __restrict__ xt,
                                              const int* __restrict__ dn,
                                              unsigned short* __restrict__ xp, int vc) {
    int wid = (blockIdx.x * blockDim.x + threadIdx.x) >> 6;
    int lane = threadIdx.x & 63;
    if (wid >= vc) return;
    float acc[8];
#pragma unroll
    for (int j = 0; j < 8; ++j) acc[j] = 0.f;
#pragma unroll
    for (int k = 0; k < 7; ++k) {
        int n = __builtin_amdgcn_readfirstlane(dn[(size_t)wid * 7 + k]);
        short8 d = *reinterpret_cast<const short8*>(xt + (size_t)n * 512 + lane * 8);
#pragma unroll
        for (int j = 0; j < 8; ++j) acc[j] += bf2f((unsigned short)d[j]);
    }
    short8 o;
#pragma unroll
    for (int j = 0; j < 8; ++j) o[j] = (short)f2bf(acc[j] * (1.f / 7.f));
    *reinterpret_cast<short8*>(xp + (size_t)wid * 512 + lane * 8) = o;
}

// ---------------------------------------------------------------------------
// Gathered conv via MFMA 16x16x32 bf16. 256-thread block = 4 waves;
// per wave 2 vertices (block = 8 verts). A-fragments read directly from
// the small L2-resident wfrag buffer (no LDS staging => no LDS occupancy
// cap, no prologue barrier). launch_bounds(256,5) caps VGPR at 102 =>
// 20+ waves/CU for latency hiding. BN stats fused in epilogue.
// xin: [vc][16][32*CCH] bf16; hout: [vc][16][64] bf16 (pre-BN).
// ---------------------------------------------------------------------------
template <int CCH>
__global__ __launch_bounds__(256, 5) void conv_mfma(const unsigned short* __restrict__ xin,
                                                    const int* __restrict__ neigh,
                                                    const unsigned short* __restrict__ wfrag,
                                                    unsigned short* __restrict__ hout,
                                                    float* __restrict__ stats,
                                                    int vc) {
    constexpr int C = 32 * CCH;
    __shared__ float bsum[128];
    if (threadIdx.x < 128) bsum[threadIdx.x] = 0.f;
    __syncthreads();

    const int wid = threadIdx.x >> 6;
    const int lane = threadIdx.x & 63;
    const int lb = lane & 15, lg = lane >> 4;
    const int v0 = blockIdx.x * 8 + wid * 2;
    const int boff = lb * C + lg * 8;   // per-lane element offset within vertex block
    const short8* __restrict__ wf = reinterpret_cast<const short8*>(wfrag);

    f32x4 acc[2][4];
#pragma unroll
    for (int i = 0; i < 2; ++i)
#pragma unroll
        for (int t = 0; t < 4; ++t) acc[i][t] = (f32x4){0.f, 0.f, 0.f, 0.f};

#pragma unroll 1
    for (int k = 0; k < 7; ++k) {
        int n0 = __builtin_amdgcn_readfirstlane((v0 < vc) ? neigh[(size_t)v0 * 7 + k] : 0);
        int n1 = __builtin_amdgcn_readfirstlane((v0 + 1 < vc) ? neigh[(size_t)(v0 + 1) * 7 + k] : 0);
#pragma unroll
        for (int ch = 0; ch < CCH; ++ch) {
            const int chunk = k * CCH + ch;
            const short8 b0 = *reinterpret_cast<const short8*>(
                xin + (size_t)n0 * (16 * C) + boff + ch * 32);
            const short8 b1 = *reinterpret_cast<const short8*>(
                xin + (size_t)n1 * (16 * C) + boff + ch * 32);
            const short8 a0 = wf[(chunk * 4 + 0) * 64 + lane];
            const short8 a1 = wf[(chunk * 4 + 1) * 64 + lane];
            const short8 a2 = wf[(chunk * 4 + 2) * 64 + lane];
            const short8 a3 = wf[(chunk * 4 + 3) * 64 + lane];
            acc[0][0] = __builtin_amdgcn_mfma_f32_16x16x32_bf16(a0, b0, acc[0][0], 0, 0, 0);
            acc[0][1] = __builtin_amdgcn_mfma_f32_16x16x32_bf16(a1, b0, acc[0][1], 0, 0, 0);
            acc[0][2] = __builtin_amdgcn_mfma_f32_16x16x32_bf16(a2, b0, acc[0][2], 0, 0, 0);
            acc[0][3] = __builtin_amdgcn_mfma_f32_16x16x32_bf16(a3, b0, acc[0][3], 0, 0, 0);
            acc[1][0] = __builtin_amdgcn_mfma_f32_16x16x32_bf16(a0, b1, acc[1][0], 0, 0, 0);
            acc[1][1] = __builtin_amdgcn_mfma_f32_16x16x32_bf16(a1, b1, acc[1][1], 0, 0, 0);
            acc[1][2] = __builtin_amdgcn_mfma_f32_16x16x32_bf16(a2, b1, acc[1][2], 0, 0, 0);
            acc[1][3] = __builtin_amdgcn_mfma_f32_16x16x32_bf16(a3, b1, acc[1][3], 0, 0, 0);
        }
    }

    // epilogue: D[o][b], o = t*16 + lg*4 + r, b = lb. Stats live only here.
    float ssum[16], ssq[16];
#pragma unroll
    for (int i = 0; i < 16; ++i) { ssum[i] = 0.f; ssq[i] = 0.f; }
#pragma unroll
    for (int i = 0; i < 2; ++i) {
        const int v = v0 + i;
        if (v < vc) {
#pragma unroll
            for (int t = 0; t < 4; ++t) {
                u16x4 st;
#pragma unroll
                for (int r = 0; r < 4; ++r) {
                    float f = acc[i][t][r];
                    ssum[t * 4 + r] += f;
                    ssq[t * 4 + r] += f * f;
                    st[r] = f2bf(f);
                }
                *reinterpret_cast<u16x4*>(hout + (size_t)v * 1024 + lb * 64 + t * 16 + lg * 4) = st;
            }
        }
    }
    // reduce over the 16 batch lanes
#pragma unroll
    for (int m = 1; m <= 8; m <<= 1) {
#pragma unroll
        for (int i = 0; i < 16; ++i) {
            ssum[i] += __shfl_xor(ssum[i], m, 64);
            ssq[i] += __shfl_xor(ssq[i], m, 64);
        }
    }
    if (lb == 0) {
#pragma unroll
        for (int t = 0; t < 4; ++t)
#pragma unroll
            for (int r = 0; r < 4; ++r) {
                int o = t * 16 + lg * 4 + r;
                atomicAdd(&bsum[o], ssum[t * 4 + r]);
                atomicAdd(&bsum[64 + o], ssq[t * 4 + r]);
            }
    }
    __syncthreads();
    if (threadIdx.x < 128) atomicAdd(&stats[threadIdx.x], bsum[threadIdx.x]);
}

// ---------------------------------------------------------------------------
// BN params: scale = gamma * rsqrt(var+eps); shift = beta - mean*scale
// ---------------------------------------------------------------------------
__global__ void bn_params(const float* __restrict__ stats, const float* __restrict__ gamma,
                          const float* __restrict__ beta, float* __restrict__ params, float inv_n) {
    int o = threadIdx.x;
    if (o < 64) {
        float mean = stats[o] * inv_n;
        float var = stats[64 + o] * inv_n - mean * mean;
        float sc = gamma[o] * rsqrtf(var + 1e-5f);
        params[o] = sc;
        params[64 + o] = beta[o] - mean * sc;
    }
}

// ---------------------------------------------------------------------------
// BN+LReLU apply in-place on h ([v][b][64] bf16)
// ---------------------------------------------------------------------------
__global__ __launch_bounds__(256) void bn_apply(unsigned short* __restrict__ h,
                                                const float* __restrict__ params, int total8) {
    int stride = gridDim.x * blockDim.x;
    int idx0 = blockIdx.x * blockDim.x + threadIdx.x;
    int c0 = (idx0 & 7) * 8;
    float sc[8], sh[8];
#pragma unroll
    for (int j = 0; j < 8; ++j) { sc[j] = params[c0 + j]; sh[j] = params[64 + c0 + j]; }
    for (int idx = idx0; idx < total8; idx += stride) {
        short8 d = *reinterpret_cast<const short8*>(h + (size_t)idx * 8);
        short8 o;
#pragma unroll
        for (int j = 0; j < 8; ++j) {
            float y = sc[j] * bf2f((unsigned short)d[j]) + sh[j];
            y = fmaxf(y, 0.2f * y);
            o[j] = (short)f2bf(y);
        }
        *reinterpret_cast<short8*>(h + (size_t)idx * 8) = o;
    }
}

// ---------------------------------------------------------------------------
// Final: BN2+LReLU on h2[v][b][o] bf16, transpose -> out[b][o][v] f32 via LDS
// ---------------------------------------------------------------------------
__global__ __launch_bounds__(256) void final_out(const unsigned short* __restrict__ h2,
                                                 const float* __restrict__ params,
                                                 float* __restrict__ out, int vc) {
    __shared__ float lds[128 * 65];
    const int t = threadIdx.x;
    const int v0 = blockIdx.x * 64;
    const int sub = t & 15, vloc = t >> 4;
    const int o0 = (sub & 7) * 8;
    float sc[8], sh[8];
#pragma unroll
    for (int j = 0; j < 8; ++j) { sc[j] = params[o0 + j]; sh[j] = params[64 + o0 + j]; }
    for (int c = 0; c < 8; ++c) {
        if (c) __syncthreads();
#pragma unroll
        for (int i = 0; i < 4; ++i) {
            int v = v0 + vloc + 16 * i;
            short8 d = {0, 0, 0, 0, 0, 0, 0, 0};
            if (v < vc)
                d = *reinterpret_cast<const short8*>(h2 + (size_t)v * 1024 + c * 128 + sub * 8);
#pragma unroll
            for (int j = 0; j < 8; ++j) {
                float y = sc[j] * bf2f((unsigned short)d[j]) + sh[j];
                y = fmaxf(y, 0.2f * y);
                lds[(sub * 8 + j) * 65 + vloc + 16 * i] = y;
            }
        }
        __syncthreads();
#pragma unroll
        for (int q = 0; q < 8; ++q) {
            int idx = t + 256 * q;       // 0..2047
            int r = idx >> 4;            // 0..127
            int vq = (idx & 15) * 4;
            int v = v0 + vq;
            const float* lp = lds + r * 65 + vq;
            if (v + 3 < vc) {
                f32x4 o = {lp[0], lp[1], lp[2], lp[3]};
                *reinterpret_cast<f32x4*>(out + (size_t)(c * 128 + r) * vc + v) = o;
            } else {
#pragma unroll
                for (int e = 0; e < 4; ++e)
                    if (v + e < vc) out[(size_t)(c * 128 + r) * vc + v + e] = lp[e];
            }
        }
    }
}

// ---------------------------------------------------------------------------
extern "C" void kernel_launch(void* const* d_in, const int* in_sizes, int n_in,
                              void* d_out, int out_size, void* d_ws, size_t ws_size,
                              hipStream_t stream) {
    const float* x   = (const float*)d_in[0];
    const float* w1  = (const float*)d_in[1];
    const float* g1  = (const float*)d_in[3];
    const float* be1 = (const float*)d_in[4];
    const float* w2  = (const float*)d_in[5];
    const float* g2  = (const float*)d_in[7];
    const float* be2 = (const float*)d_in[8];
    const int* cn    = (const int*)d_in[9];
    const int* dn    = (const int*)d_in[10];
    float* out = (float*)d_out;

    // workspace layout (~210 MB)
    char* ws = (char*)d_ws;
    size_t off = 0;
    auto take = [&](size_t bytes) { size_t o = off; off = (off + bytes + 255) & ~(size_t)255; return o; };
    unsigned short* xp  = (unsigned short*)(ws + take((size_t)VC * 512 * 2));
    unsigned short* h1  = (unsigned short*)(ws + take((size_t)VC * 1024 * 2));
    unsigned short* h2  = (unsigned short*)(ws + take((size_t)VC * 1024 * 2));
    unsigned short* w1f = (unsigned short*)(ws + take(7 * 4 * 64 * 8 * 2));
    unsigned short* w2f = (unsigned short*)(ws + take(14 * 4 * 64 * 8 * 2));
    float* stats        = (float*)(ws + take(256 * 4));       // [sum1|sq1|sum2|sq2]
    float* params       = (float*)(ws + take(256 * 4));       // [sc1|sh1|sc2|sh2]

    // xt (bf16 transposed fine grid) lives in d_out as scratch (dead before final_out)
    unsigned short* xt = (unsigned short*)d_out;

    const float inv_n = 1.0f / (16.0f * (float)VC);
    const int nblk = (VC + 7) / 8;   // 8 verts per 256-thread conv block

    prep_w<<<32, 256, 0, stream>>>(w1, w2, w1f, w2f, stats);
    transpose_x<<<(VFINE + 63) / 64, 256, 0, stream>>>(x, xt, VFINE);
    pool_k<<<(VC + 3) / 4, 256, 0, stream>>>(xt, dn, xp, VC);
    conv_mfma<1><<<nblk, 256, 0, stream>>>(xp, cn, w1f, h1, stats, VC);
    bn_params<<<1, 64, 0, stream>>>(stats, g1, be1, params, inv_n);
    bn_apply<<<2048, 256, 0, stream>>>(h1, params, VC * 128);
    conv_mfma<2><<<nblk, 256, 0, stream>>>(h1, cn, w2f, h2, stats + 128, VC);
    bn_params<<<1, 64, 0, stream>>>(stats + 128, g2, be2, params + 128, inv_n);
    final_out<<<(VC + 63) / 64, 256, 0, stream>>>(h2, params + 128, out, VC);
}

// Round 7
// 544.446 us; speedup vs baseline: 1.1075x; 1.1075x over previous
//
#include <hip/hip_runtime.h>
#include <hip/hip_bf16.h>

// DownBlock: pool(mean over 7 down-neighbors) -> conv1(K=7, 32->64) -> BN+LReLU
//         -> conv2(K=7, 64->64) -> BN+LReLU
// B=16, C_IN=32, C=64, V_FINE=163842, V=40962, K=7.
// Biases b1/b2 are dead: BN's mean subtraction absorbs per-channel constants.
// Convs are bound by gather latency x per-wave MLP (R5 vs R6 A/B):
// R7 = R5 conv shell (512thr, LDS weights, 4 verts/wave, LB(512,4))
//      + explicit 1-chunk-ahead B-gather double-buffer (8-deep MLP/wave).

#define B_SZ     16
#define CIN      32
#define CMID     64
#define VFINE    163842
#define VC       40962
#define KNB      7

typedef __attribute__((ext_vector_type(8))) short  short8;   // 8 x bf16 (as i16)
typedef __attribute__((ext_vector_type(4))) float  f32x4;
typedef __attribute__((ext_vector_type(4))) unsigned short u16x4;

__device__ inline float bf2f(unsigned short u) {
    return __builtin_bit_cast(float, (unsigned int)(((unsigned int)u) << 16));
}
__device__ inline unsigned short f2bf(float f) {
    __hip_bfloat16 h = __float2bfloat16(f);
    return __builtin_bit_cast(unsigned short, h);
}

// ---------------------------------------------------------------------------
// Prep: reorder W into per-lane MFMA A-fragments, bf16. Also zeroes stats.
// Fragment (chunk, otile): lane l, elem j ->  A[o = otile*16 + (l&15)][kk = (l>>4)*8 + j]
// conv1: chunk cc = k (7 chunks), c = kk.        W1[o][c*7+k]
// conv2: chunk cc = k*2 + ch (14), c = ch*32+kk. W2[o][c*7+k]
// ---------------------------------------------------------------------------
__global__ void prep_w(const float* __restrict__ w1, const float* __restrict__ w2,
                       unsigned short* __restrict__ w1f, unsigned short* __restrict__ w2f,
                       float* __restrict__ stats) {
    int tid = blockIdx.x * blockDim.x + threadIdx.x;
    int stride = gridDim.x * blockDim.x;
    if (blockIdx.x == 0 && threadIdx.x < 256) stats[threadIdx.x] = 0.f;
    const int total1 = 7 * 4 * 64 * 8;
    for (int idx = tid; idx < total1; idx += stride) {
        int j = idx & 7, l = (idx >> 3) & 63, t = (idx >> 9) & 3, cc = idx >> 11;
        int o = t * 16 + (l & 15);
        int kk = (l >> 4) * 8 + j;
        w1f[idx] = f2bf(w1[o * 224 + kk * 7 + cc]);
    }
    const int total2 = 14 * 4 * 64 * 8;
    for (int idx = tid; idx < total2; idx += stride) {
        int j = idx & 7, l = (idx >> 3) & 63, t = (idx >> 9) & 3, cc = idx >> 11;
        int o = t * 16 + (l & 15);
        int kk = (l >> 4) * 8 + j;
        int k = cc >> 1, ch = cc & 1;
        int c = ch * 32 + kk;
        w2f[idx] = f2bf(w2[o * 448 + c * 7 + k]);
    }
}

// ---------------------------------------------------------------------------
// Transpose x (512 rows x VFINE) f32 -> xt[v][512] bf16.
// 64-vertex tile, two 256-channel phases. LDS [64 verts][258 u16] (33KB).
// ---------------------------------------------------------------------------
__global__ __launch_bounds__(256) void transpose_x(const float* __restrict__ x,
                                                   unsigned short* __restrict__ xt, int vf) {
    __shared__ __align__(16) unsigned short lds[64 * 258];
    const int t = threadIdx.x;
    const int v0 = blockIdx.x * 64;
    const int j  = t & 15;        // load phase: vert group (4 verts)
    const int r0 = t >> 4;        // load phase: row base
    const int lane = t & 63;
    const int wid = t >> 6;

#pragma unroll
    for (int p = 0; p < 2; ++p) {
        if (p) __syncthreads();
#pragma unroll
        for (int it = 0; it < 16; ++it) {
            int r = r0 + it * 16;          // row within phase 0..255
            int row = p * 256 + r;
            int vg = v0 + 4 * j;
            f32x4 d = {0.f, 0.f, 0.f, 0.f};
            if (vg + 3 < vf) {
                d = *reinterpret_cast<const f32x4*>(x + (size_t)row * vf + vg);
            } else {
#pragma unroll
                for (int q = 0; q < 4; ++q)
                    if (vg + q < vf) d[q] = x[(size_t)row * vf + vg + q];
            }
#pragma unroll
            for (int q = 0; q < 4; ++q)
                lds[(4 * j + q) * 258 + r] = f2bf(d[q]);
        }
        __syncthreads();
#pragma unroll
        for (int i = 0; i < 16; ++i) {
            int v = wid * 16 + i;
            u16x4 o = *reinterpret_cast<const u16x4*>(lds + v * 258 + 4 * lane);
            if (v0 + v < vf)
                *reinterpret_cast<u16x4*>(xt + (size_t)(v0 + v) * 512 + p * 256 + 4 * lane) = o;
        }
    }
}

// ---------------------------------------------------------------------------
// Pool: xp[v][b][c] = mean_k xt[dn[v][k]][b][c]. One wave per coarse vertex.
// ---------------------------------------------------------------------------
__global__ __launch_bounds__(256) void pool_k(const unsigned short* __restrict__ xt,
                                              const int* __restrict__ dn,
                                              unsigned short* __restrict__ xp, int vc) {
    int wid = (blockIdx.x * blockDim.x + threadIdx.x) >> 6;
    int lane = threadIdx.x & 63;
    if (wid >= vc) return;
    float acc[8];
#pragma unroll
    for (int j = 0; j < 8; ++j) acc[j] = 0.f;
#pragma unroll
    for (int k = 0; k < 7; ++k) {
        int n = __builtin_amdgcn_readfirstlane(dn[(size_t)wid * 7 + k]);
        short8 d = *reinterpret_cast<const short8*>(xt + (size_t)n * 512 + lane * 8);
#pragma unroll
        for (int j = 0; j < 8; ++j) acc[j] += bf2f((unsigned short)d[j]);
    }
    short8 o;
#pragma unroll
    for (int j = 0; j < 8; ++j) o[j] = (short)f2bf(acc[j] * (1.f / 7.f));
    *reinterpret_cast<short8*>(xp + (size_t)wid * 512 + lane * 8) = o;
}

// ---------------------------------------------------------------------------
// Gathered conv via MFMA 16x16x32 bf16. 512-thread block = 8 waves;
// 4 verts/wave (block = 32 verts). Weights LDS-staged. Chunk loop fully
// unrolled with a 1-chunk-ahead B-gather double-buffer: chunk i+1's 4
// gathers are in flight while chunk i's 16 MFMAs execute (8-deep MLP).
// BN stats fused in epilogue. xin: [vc][16][32*CCH]; hout: [vc][16][64].
// ---------------------------------------------------------------------------
template <int CCH>
__global__ __launch_bounds__(512, 4) void conv_mfma(const unsigned short* __restrict__ xin,
                                                    const int* __restrict__ neigh,
                                                    const unsigned short* __restrict__ wfrag,
                                                    unsigned short* __restrict__ hout,
                                                    float* __restrict__ stats,
                                                    int vc) {
    constexpr int C = 32 * CCH;
    constexpr int NCHUNK = 7 * CCH;
    __shared__ __align__(16) unsigned short wlds[NCHUNK * 2048];
    __shared__ float bsum[128];
    for (int i = threadIdx.x; i < NCHUNK * 256; i += 512)
        reinterpret_cast<short8*>(wlds)[i] = reinterpret_cast<const short8*>(wfrag)[i];
    if (threadIdx.x < 128) bsum[threadIdx.x] = 0.f;
    __syncthreads();

    const int wid = threadIdx.x >> 6;
    const int lane = threadIdx.x & 63;
    const int lb = lane & 15, lg = lane >> 4;
    const int v0 = blockIdx.x * 32 + wid * 4;
    const int boff = lb * C + lg * 8;   // per-lane element offset within vertex block

    f32x4 acc[4][4];
#pragma unroll
    for (int i = 0; i < 4; ++i)
#pragma unroll
        for (int t = 0; t < 4; ++t) acc[i][t] = (f32x4){0.f, 0.f, 0.f, 0.f};

    // wave-uniform gather base for (k, vert i)
    auto nbase = [&](int k, int i) -> const unsigned short* {
        int v = v0 + i;
        int n = __builtin_amdgcn_readfirstlane((v < vc) ? neigh[(size_t)v * 7 + k] : 0);
        return xin + (size_t)n * (16 * C);
    };

    short8 bbuf[2][4];
    // prologue: prefetch chunk 0 (k=0, ch=0)
#pragma unroll
    for (int i = 0; i < 4; ++i)
        bbuf[0][i] = *reinterpret_cast<const short8*>(nbase(0, i) + boff);

#pragma unroll
    for (int cidx = 0; cidx < NCHUNK; ++cidx) {
        const int cur = cidx & 1, nxt = cur ^ 1;
        if (cidx + 1 < NCHUNK) {
            const int k2 = (cidx + 1) / CCH, ch2 = (cidx + 1) % CCH;
#pragma unroll
            for (int i = 0; i < 4; ++i)
                bbuf[nxt][i] = *reinterpret_cast<const short8*>(nbase(k2, i) + boff + ch2 * 32);
        }
        const short8* wp = reinterpret_cast<const short8*>(wlds) + (cidx * 4) * 64 + lane;
        const short8 a0 = wp[0];
        const short8 a1 = wp[64];
        const short8 a2 = wp[128];
        const short8 a3 = wp[192];
#pragma unroll
        for (int i = 0; i < 4; ++i) {
            acc[i][0] = __builtin_amdgcn_mfma_f32_16x16x32_bf16(a0, bbuf[cur][i], acc[i][0], 0, 0, 0);
            acc[i][1] = __builtin_amdgcn_mfma_f32_16x16x32_bf16(a1, bbuf[cur][i], acc[i][1], 0, 0, 0);
            acc[i][2] = __builtin_amdgcn_mfma_f32_16x16x32_bf16(a2, bbuf[cur][i], acc[i][2], 0, 0, 0);
            acc[i][3] = __builtin_amdgcn_mfma_f32_16x16x32_bf16(a3, bbuf[cur][i], acc[i][3], 0, 0, 0);
        }
    }

    // epilogue: D[o][b], o = t*16 + lg*4 + r, b = lb. Stats live only here.
    float ssum[16], ssq[16];
#pragma unroll
    for (int i = 0; i < 16; ++i) { ssum[i] = 0.f; ssq[i] = 0.f; }
#pragma unroll
    for (int i = 0; i < 4; ++i) {
        const int v = v0 + i;
        if (v < vc) {
#pragma unroll
            for (int t = 0; t < 4; ++t) {
                u16x4 st;
#pragma unroll
                for (int r = 0; r < 4; ++r) {
                    float f = acc[i][t][r];
                    ssum[t * 4 + r] += f;
                    ssq[t * 4 + r] += f * f;
                    st[r] = f2bf(f);
                }
                *reinterpret_cast<u16x4*>(hout + (size_t)v * 1024 + lb * 64 + t * 16 + lg * 4) = st;
            }
        }
    }
    // reduce over the 16 batch lanes
#pragma unroll
    for (int m = 1; m <= 8; m <<= 1) {
#pragma unroll
        for (int i = 0; i < 16; ++i) {
            ssum[i] += __shfl_xor(ssum[i], m, 64);
            ssq[i] += __shfl_xor(ssq[i], m, 64);
        }
    }
    if (lb == 0) {
#pragma unroll
        for (int t = 0; t < 4; ++t)
#pragma unroll
            for (int r = 0; r < 4; ++r) {
                int o = t * 16 + lg * 4 + r;
                atomicAdd(&bsum[o], ssum[t * 4 + r]);
                atomicAdd(&bsum[64 + o], ssq[t * 4 + r]);
            }
    }
    __syncthreads();
    if (threadIdx.x < 128) atomicAdd(&stats[threadIdx.x], bsum[threadIdx.x]);
}

// ---------------------------------------------------------------------------
// BN params: scale = gamma * rsqrt(var+eps); shift = beta - mean*scale
// ---------------------------------------------------------------------------
__global__ void bn_params(const float* __restrict__ stats, const float* __restrict__ gamma,
                          const float* __restrict__ beta, float* __restrict__ params, float inv_n) {
    int o = threadIdx.x;
    if (o < 64) {
        float mean = stats[o] * inv_n;
        float var = stats[64 + o] * inv_n - mean * mean;
        float sc = gamma[o] * rsqrtf(var + 1e-5f);
        params[o] = sc;
        params[64 + o] = beta[o] - mean * sc;
    }
}

// ---------------------------------------------------------------------------
// BN+LReLU apply in-place on h ([v][b][64] bf16)
// ---------------------------------------------------------------------------
__global__ __launch_bounds__(256) void bn_apply(unsigned short* __restrict__ h,
                                                const float* __restrict__ params, int total8) {
    int stride = gridDim.x * blockDim.x;
    int idx0 = blockIdx.x * blockDim.x + threadIdx.x;
    int c0 = (idx0 & 7) * 8;
    float sc[8], sh[8];
#pragma unroll
    for (int j = 0; j < 8; ++j) { sc[j] = params[c0 + j]; sh[j] = params[64 + c0 + j]; }
    for (int idx = idx0; idx < total8; idx += stride) {
        short8 d = *reinterpret_cast<const short8*>(h + (size_t)idx * 8);
        short8 o;
#pragma unroll
        for (int j = 0; j < 8; ++j) {
            float y = sc[j] * bf2f((unsigned short)d[j]) + sh[j];
            y = fmaxf(y, 0.2f * y);
            o[j] = (short)f2bf(y);
        }
        *reinterpret_cast<short8*>(h + (size_t)idx * 8) = o;
    }
}

// ---------------------------------------------------------------------------
// Final: BN2+LReLU on h2[v][b][o] bf16, transpose -> out[b][o][v] f32 via LDS
// ---------------------------------------------------------------------------
__global__ __launch_bounds__(256) void final_out(const unsigned short* __restrict__ h2,
                                                 const float* __restrict__ params,
                                                 float* __restrict__ out, int vc) {
    __shared__ float lds[128 * 65];
    const int t = threadIdx.x;
    const int v0 = blockIdx.x * 64;
    const int sub = t & 15, vloc = t >> 4;
    const int o0 = (sub & 7) * 8;
    float sc[8], sh[8];
#pragma unroll
    for (int j = 0; j < 8; ++j) { sc[j] = params[o0 + j]; sh[j] = params[64 + o0 + j]; }
    for (int c = 0; c < 8; ++c) {
        if (c) __syncthreads();
#pragma unroll
        for (int i = 0; i < 4; ++i) {
            int v = v0 + vloc + 16 * i;
            short8 d = {0, 0, 0, 0, 0, 0, 0, 0};
            if (v < vc)
                d = *reinterpret_cast<const short8*>(h2 + (size_t)v * 1024 + c * 128 + sub * 8);
#pragma unroll
            for (int j = 0; j < 8; ++j) {
                float y = sc[j] * bf2f((unsigned short)d[j]) + sh[j];
                y = fmaxf(y, 0.2f * y);
                lds[(sub * 8 + j) * 65 + vloc + 16 * i] = y;
            }
        }
        __syncthreads();
#pragma unroll
        for (int q = 0; q < 8; ++q) {
            int idx = t + 256 * q;       // 0..2047
            int r = idx >> 4;            // 0..127
            int vq = (idx & 15) * 4;
            int v = v0 + vq;
            const float* lp = lds + r * 65 + vq;
            if (v + 3 < vc) {
                f32x4 o = {lp[0], lp[1], lp[2], lp[3]};
                *reinterpret_cast<f32x4*>(out + (size_t)(c * 128 + r) * vc + v) = o;
            } else {
#pragma unroll
                for (int e = 0; e < 4; ++e)
                    if (v + e < vc) out[(size_t)(c * 128 + r) * vc + v + e] = lp[e];
            }
        }
    }
}

// ---------------------------------------------------------------------------
extern "C" void kernel_launch(void* const* d_in, const int* in_sizes, int n_in,
                              void* d_out, int out_size, void* d_ws, size_t ws_size,
                              hipStream_t stream) {
    const float* x   = (const float*)d_in[0];
    const float* w1  = (const float*)d_in[1];
    const float* g1  = (const float*)d_in[3];
    const float* be1 = (const float*)d_in[4];
    const float* w2  = (const float*)d_in[5];
    const float* g2  = (const float*)d_in[7];
    const float* be2 = (const float*)d_in[8];
    const int* cn    = (const int*)d_in[9];
    const int* dn    = (const int*)d_in[10];
    float* out = (float*)d_out;

    // workspace layout (~210 MB)
    char* ws = (char*)d_ws;
    size_t off = 0;
    auto take = [&](size_t bytes) { size_t o = off; off = (off + bytes + 255) & ~(size_t)255; return o; };
    unsigned short* xp  = (unsigned short*)(ws + take((size_t)VC * 512 * 2));
    unsigned short* h1  = (unsigned short*)(ws + take((size_t)VC * 1024 * 2));
    unsigned short* h2  = (unsigned short*)(ws + take((size_t)VC * 1024 * 2));
    unsigned short* w1f = (unsigned short*)(ws + take(7 * 4 * 64 * 8 * 2));
    unsigned short* w2f = (unsigned short*)(ws + take(14 * 4 * 64 * 8 * 2));
    float* stats        = (float*)(ws + take(256 * 4));       // [sum1|sq1|sum2|sq2]
    float* params       = (float*)(ws + take(256 * 4));       // [sc1|sh1|sc2|sh2]

    // xt (bf16 transposed fine grid) lives in d_out as scratch (dead before final_out)
    unsigned short* xt = (unsigned short*)d_out;

    const float inv_n = 1.0f / (16.0f * (float)VC);
    const int nblk = (VC + 31) / 32;   // 32 verts per 512-thread conv block

    prep_w<<<32, 256, 0, stream>>>(w1, w2, w1f, w2f, stats);
    transpose_x<<<(VFINE + 63) / 64, 256, 0, stream>>>(x, xt, VFINE);
    pool_k<<<(VC + 3) / 4, 256, 0, stream>>>(xt, dn, xp, VC);
    conv_mfma<1><<<nblk, 512, 0, stream>>>(xp, cn, w1f, h1, stats, VC);
    bn_params<<<1, 64, 0, stream>>>(stats, g1, be1, params, inv_n);
    bn_apply<<<2048, 256, 0, stream>>>(h1, params, VC * 128);
    conv_mfma<2><<<nblk, 512, 0, stream>>>(h1, cn, w2f, h2, stats + 128, VC);
    bn_params<<<1, 64, 0, stream>>>(stats + 128, g2, be2, params + 128, inv_n);
    final_out<<<(VC + 63) / 64, 256, 0, stream>>>(h2, params + 128, out, VC);
}

// Round 8
// 525.972 us; speedup vs baseline: 1.1464x; 1.0351x over previous
//
#include <hip/hip_runtime.h>
#include <hip/hip_bf16.h>

// DownBlock: pool(mean over 7 down-neighbors) -> conv1(K=7, 32->64) -> BN+LReLU
//         -> conv2(K=7, 64->64) -> BN+LReLU
// B=16, C_IN=32, C=64, V_FINE=163842, V=40962, K=7.
// Biases b1/b2 are dead: BN's mean subtraction absorbs per-channel constants.
// Conv critical path = idx-load -> gather -> MFMA (two chained latencies).
// R8 = R5 shell (512thr, LDS weights, 4 verts/wave, LB(512,4), unroll 1)
//      + ALL neighbor indices hoisted to SGPRs before the k-loop.

#define B_SZ     16
#define CIN      32
#define CMID     64
#define VFINE    163842
#define VC       40962
#define KNB      7

typedef __attribute__((ext_vector_type(8))) short  short8;   // 8 x bf16 (as i16)
typedef __attribute__((ext_vector_type(4))) float  f32x4;
typedef __attribute__((ext_vector_type(4))) unsigned short u16x4;

__device__ inline float bf2f(unsigned short u) {
    return __builtin_bit_cast(float, (unsigned int)(((unsigned int)u) << 16));
}
__device__ inline unsigned short f2bf(float f) {
    __hip_bfloat16 h = __float2bfloat16(f);
    return __builtin_bit_cast(unsigned short, h);
}

// ---------------------------------------------------------------------------
// Prep: reorder W into per-lane MFMA A-fragments, bf16. Also zeroes stats.
// Fragment (chunk, otile): lane l, elem j ->  A[o = otile*16 + (l&15)][kk = (l>>4)*8 + j]
// conv1: chunk cc = k (7 chunks), c = kk.        W1[o][c*7+k]
// conv2: chunk cc = k*2 + ch (14), c = ch*32+kk. W2[o][c*7+k]
// ---------------------------------------------------------------------------
__global__ void prep_w(const float* __restrict__ w1, const float* __restrict__ w2,
                       unsigned short* __restrict__ w1f, unsigned short* __restrict__ w2f,
                       float* __restrict__ stats) {
    int tid = blockIdx.x * blockDim.x + threadIdx.x;
    int stride = gridDim.x * blockDim.x;
    if (blockIdx.x == 0 && threadIdx.x < 256) stats[threadIdx.x] = 0.f;
    const int total1 = 7 * 4 * 64 * 8;
    for (int idx = tid; idx < total1; idx += stride) {
        int j = idx & 7, l = (idx >> 3) & 63, t = (idx >> 9) & 3, cc = idx >> 11;
        int o = t * 16 + (l & 15);
        int kk = (l >> 4) * 8 + j;
        w1f[idx] = f2bf(w1[o * 224 + kk * 7 + cc]);
    }
    const int total2 = 14 * 4 * 64 * 8;
    for (int idx = tid; idx < total2; idx += stride) {
        int j = idx & 7, l = (idx >> 3) & 63, t = (idx >> 9) & 3, cc = idx >> 11;
        int o = t * 16 + (l & 15);
        int kk = (l >> 4) * 8 + j;
        int k = cc >> 1, ch = cc & 1;
        int c = ch * 32 + kk;
        w2f[idx] = f2bf(w2[o * 448 + c * 7 + k]);
    }
}

// ---------------------------------------------------------------------------
// Transpose x (512 rows x VFINE) f32 -> xt[v][512] bf16.
// 64-vertex tile, two 256-channel phases. LDS [64 verts][258 u16] (33KB).
// ---------------------------------------------------------------------------
__global__ __launch_bounds__(256) void transpose_x(const float* __restrict__ x,
                                                   unsigned short* __restrict__ xt, int vf) {
    __shared__ __align__(16) unsigned short lds[64 * 258];
    const int t = threadIdx.x;
    const int v0 = blockIdx.x * 64;
    const int j  = t & 15;        // load phase: vert group (4 verts)
    const int r0 = t >> 4;        // load phase: row base
    const int lane = t & 63;
    const int wid = t >> 6;

#pragma unroll
    for (int p = 0; p < 2; ++p) {
        if (p) __syncthreads();
#pragma unroll
        for (int it = 0; it < 16; ++it) {
            int r = r0 + it * 16;          // row within phase 0..255
            int row = p * 256 + r;
            int vg = v0 + 4 * j;
            f32x4 d = {0.f, 0.f, 0.f, 0.f};
            if (vg + 3 < vf) {
                d = *reinterpret_cast<const f32x4*>(x + (size_t)row * vf + vg);
            } else {
#pragma unroll
                for (int q = 0; q < 4; ++q)
                    if (vg + q < vf) d[q] = x[(size_t)row * vf + vg + q];
            }
#pragma unroll
            for (int q = 0; q < 4; ++q)
                lds[(4 * j + q) * 258 + r] = f2bf(d[q]);
        }
        __syncthreads();
#pragma unroll
        for (int i = 0; i < 16; ++i) {
            int v = wid * 16 + i;
            u16x4 o = *reinterpret_cast<const u16x4*>(lds + v * 258 + 4 * lane);
            if (v0 + v < vf)
                *reinterpret_cast<u16x4*>(xt + (size_t)(v0 + v) * 512 + p * 256 + 4 * lane) = o;
        }
    }
}

// ---------------------------------------------------------------------------
// Pool: xp[v][b][c] = mean_k xt[dn[v][k]][b][c]. One wave per coarse vertex.
// All 7 indices hoisted before the gather loop.
// ---------------------------------------------------------------------------
__global__ __launch_bounds__(256) void pool_k(const unsigned short* __restrict__ xt,
                                              const int* __restrict__ dn,
                                              unsigned short* __restrict__ xp, int vc) {
    int wid = (blockIdx.x * blockDim.x + threadIdx.x) >> 6;
    int lane = threadIdx.x & 63;
    if (wid >= vc) return;
    int nn[7];
#pragma unroll
    for (int k = 0; k < 7; ++k)
        nn[k] = __builtin_amdgcn_readfirstlane(dn[(size_t)wid * 7 + k]);
    float acc[8];
#pragma unroll
    for (int j = 0; j < 8; ++j) acc[j] = 0.f;
#pragma unroll
    for (int k = 0; k < 7; ++k) {
        short8 d = *reinterpret_cast<const short8*>(xt + (size_t)nn[k] * 512 + lane * 8);
#pragma unroll
        for (int j = 0; j < 8; ++j) acc[j] += bf2f((unsigned short)d[j]);
    }
    short8 o;
#pragma unroll
    for (int j = 0; j < 8; ++j) o[j] = (short)f2bf(acc[j] * (1.f / 7.f));
    *reinterpret_cast<short8*>(xp + (size_t)wid * 512 + lane * 8) = o;
}

// ---------------------------------------------------------------------------
// Gathered conv via MFMA 16x16x32 bf16. 512-thread block = 8 waves;
// 4 verts/wave (block = 32 verts). Weights LDS-staged. All 28 neighbor
// indices (4 verts x 7 k) hoisted to SGPRs before the k-loop so every
// gather address is register-ready; per-iter chain is gather->MFMA only.
// BN stats fused in epilogue. xin: [vc][16][32*CCH]; hout: [vc][16][64].
// ---------------------------------------------------------------------------
template <int CCH>
__global__ __launch_bounds__(512, 4) void conv_mfma(const unsigned short* __restrict__ xin,
                                                    const int* __restrict__ neigh,
                                                    const unsigned short* __restrict__ wfrag,
                                                    unsigned short* __restrict__ hout,
                                                    float* __restrict__ stats,
                                                    int vc) {
    constexpr int C = 32 * CCH;
    constexpr int NCHUNK = 7 * CCH;
    __shared__ __align__(16) unsigned short wlds[NCHUNK * 2048];
    __shared__ float bsum[128];
    for (int i = threadIdx.x; i < NCHUNK * 256; i += 512)
        reinterpret_cast<short8*>(wlds)[i] = reinterpret_cast<const short8*>(wfrag)[i];
    if (threadIdx.x < 128) bsum[threadIdx.x] = 0.f;
    __syncthreads();

    const int wid = threadIdx.x >> 6;
    const int lane = threadIdx.x & 63;
    const int lb = lane & 15, lg = lane >> 4;
    const int v0 = blockIdx.x * 32 + wid * 4;
    const int boff = lb * C + lg * 8;   // per-lane element offset within vertex block

    // hoist all neighbor indices into SGPRs (wave-uniform)
    int nn[7][4];
#pragma unroll
    for (int i = 0; i < 4; ++i) {
        const int v = v0 + i;
        const bool ok = (v < vc);
#pragma unroll
        for (int k = 0; k < 7; ++k)
            nn[k][i] = __builtin_amdgcn_readfirstlane(ok ? neigh[(size_t)v * 7 + k] : 0);
    }

    f32x4 acc[4][4];
#pragma unroll
    for (int i = 0; i < 4; ++i)
#pragma unroll
        for (int t = 0; t < 4; ++t) acc[i][t] = (f32x4){0.f, 0.f, 0.f, 0.f};

#pragma unroll (CCH == 1 ? 2 : 1)
    for (int k = 0; k < 7; ++k) {
#pragma unroll
        for (int ch = 0; ch < CCH; ++ch) {
            const int chunk = k * CCH + ch;
            const short8* wp = reinterpret_cast<const short8*>(wlds) + (chunk * 4) * 64 + lane;
            const short8 a0 = wp[0];
            const short8 a1 = wp[64];
            const short8 a2 = wp[128];
            const short8 a3 = wp[192];
#pragma unroll
            for (int i = 0; i < 4; ++i) {
                const short8 b = *reinterpret_cast<const short8*>(
                    xin + (size_t)nn[k][i] * (16 * C) + boff + ch * 32);
                acc[i][0] = __builtin_amdgcn_mfma_f32_16x16x32_bf16(a0, b, acc[i][0], 0, 0, 0);
                acc[i][1] = __builtin_amdgcn_mfma_f32_16x16x32_bf16(a1, b, acc[i][1], 0, 0, 0);
                acc[i][2] = __builtin_amdgcn_mfma_f32_16x16x32_bf16(a2, b, acc[i][2], 0, 0, 0);
                acc[i][3] = __builtin_amdgcn_mfma_f32_16x16x32_bf16(a3, b, acc[i][3], 0, 0, 0);
            }
        }
    }

    // epilogue: D[o][b], o = t*16 + lg*4 + r, b = lb. Stats live only here.
    float ssum[16], ssq[16];
#pragma unroll
    for (int i = 0; i < 16; ++i) { ssum[i] = 0.f; ssq[i] = 0.f; }
#pragma unroll
    for (int i = 0; i < 4; ++i) {
        const int v = v0 + i;
        if (v < vc) {
#pragma unroll
            for (int t = 0; t < 4; ++t) {
                u16x4 st;
#pragma unroll
                for (int r = 0; r < 4; ++r) {
                    float f = acc[i][t][r];
                    ssum[t * 4 + r] += f;
                    ssq[t * 4 + r] += f * f;
                    st[r] = f2bf(f);
                }
                *reinterpret_cast<u16x4*>(hout + (size_t)v * 1024 + lb * 64 + t * 16 + lg * 4) = st;
            }
        }
    }
    // reduce over the 16 batch lanes
#pragma unroll
    for (int m = 1; m <= 8; m <<= 1) {
#pragma unroll
        for (int i = 0; i < 16; ++i) {
            ssum[i] += __shfl_xor(ssum[i], m, 64);
            ssq[i] += __shfl_xor(ssq[i], m, 64);
        }
    }
    if (lb == 0) {
#pragma unroll
        for (int t = 0; t < 4; ++t)
#pragma unroll
            for (int r = 0; r < 4; ++r) {
                int o = t * 16 + lg * 4 + r;
                atomicAdd(&bsum[o], ssum[t * 4 + r]);
                atomicAdd(&bsum[64 + o], ssq[t * 4 + r]);
            }
    }
    __syncthreads();
    if (threadIdx.x < 128) atomicAdd(&stats[threadIdx.x], bsum[threadIdx.x]);
}

// ---------------------------------------------------------------------------
// BN params: scale = gamma * rsqrt(var+eps); shift = beta - mean*scale
// ---------------------------------------------------------------------------
__global__ void bn_params(const float* __restrict__ stats, const float* __restrict__ gamma,
                          const float* __restrict__ beta, float* __restrict__ params, float inv_n) {
    int o = threadIdx.x;
    if (o < 64) {
        float mean = stats[o] * inv_n;
        float var = stats[64 + o] * inv_n - mean * mean;
        float sc = gamma[o] * rsqrtf(var + 1e-5f);
        params[o] = sc;
        params[64 + o] = beta[o] - mean * sc;
    }
}

// ---------------------------------------------------------------------------
// BN+LReLU apply in-place on h ([v][b][64] bf16)
// ---------------------------------------------------------------------------
__global__ __launch_bounds__(256) void bn_apply(unsigned short* __restrict__ h,
                                                const float* __restrict__ params, int total8) {
    int stride = gridDim.x * blockDim.x;
    int idx0 = blockIdx.x * blockDim.x + threadIdx.x;
    int c0 = (idx0 & 7) * 8;
    float sc[8], sh[8];
#pragma unroll
    for (int j = 0; j < 8; ++j) { sc[j] = params[c0 + j]; sh[j] = params[64 + c0 + j]; }
    for (int idx = idx0; idx < total8; idx += stride) {
        short8 d = *reinterpret_cast<const short8*>(h + (size_t)idx * 8);
        short8 o;
#pragma unroll
        for (int j = 0; j < 8; ++j) {
            float y = sc[j] * bf2f((unsigned short)d[j]) + sh[j];
            y = fmaxf(y, 0.2f * y);
            o[j] = (short)f2bf(y);
        }
        *reinterpret_cast<short8*>(h + (size_t)idx * 8) = o;
    }
}

// ---------------------------------------------------------------------------
// Final: BN2+LReLU on h2[v][b][o] bf16, transpose -> out[b][o][v] f32 via LDS
// ---------------------------------------------------------------------------
__global__ __launch_bounds__(256) void final_out(const unsigned short* __restrict__ h2,
                                                 const float* __restrict__ params,
                                                 float* __restrict__ out, int vc) {
    __shared__ float lds[128 * 65];
    const int t = threadIdx.x;
    const int v0 = blockIdx.x * 64;
    const int sub = t & 15, vloc = t >> 4;
    const int o0 = (sub & 7) * 8;
    float sc[8], sh[8];
#pragma unroll
    for (int j = 0; j < 8; ++j) { sc[j] = params[o0 + j]; sh[j] = params[64 + o0 + j]; }
    for (int c = 0; c < 8; ++c) {
        if (c) __syncthreads();
#pragma unroll
        for (int i = 0; i < 4; ++i) {
            int v = v0 + vloc + 16 * i;
            short8 d = {0, 0, 0, 0, 0, 0, 0, 0};
            if (v < vc)
                d = *reinterpret_cast<const short8*>(h2 + (size_t)v * 1024 + c * 128 + sub * 8);
#pragma unroll
            for (int j = 0; j < 8; ++j) {
                float y = sc[j] * bf2f((unsigned short)d[j]) + sh[j];
                y = fmaxf(y, 0.2f * y);
                lds[(sub * 8 + j) * 65 + vloc + 16 * i] = y;
            }
        }
        __syncthreads();
#pragma unroll
        for (int q = 0; q < 8; ++q) {
            int idx = t + 256 * q;       // 0..2047
            int r = idx >> 4;            // 0..127
            int vq = (idx & 15) * 4;
            int v = v0 + vq;
            const float* lp = lds + r * 65 + vq;
            if (v + 3 < vc) {
                f32x4 o = {lp[0], lp[1], lp[2], lp[3]};
                *reinterpret_cast<f32x4*>(out + (size_t)(c * 128 + r) * vc + v) = o;
            } else {
#pragma unroll
                for (int e = 0; e < 4; ++e)
                    if (v + e < vc) out[(size_t)(c * 128 + r) * vc + v + e] = lp[e];
            }
        }
    }
}

// ---------------------------------------------------------------------------
extern "C" void kernel_launch(void* const* d_in, const int* in_sizes, int n_in,
                              void* d_out, int out_size, void* d_ws, size_t ws_size,
                              hipStream_t stream) {
    const float* x   = (const float*)d_in[0];
    const float* w1  = (const float*)d_in[1];
    const float* g1  = (const float*)d_in[3];
    const float* be1 = (const float*)d_in[4];
    const float* w2  = (const float*)d_in[5];
    const float* g2  = (const float*)d_in[7];
    const float* be2 = (const float*)d_in[8];
    const int* cn    = (const int*)d_in[9];
    const int* dn    = (const int*)d_in[10];
    float* out = (float*)d_out;

    // workspace layout (~210 MB)
    char* ws = (char*)d_ws;
    size_t off = 0;
    auto take = [&](size_t bytes) { size_t o = off; off = (off + bytes + 255) & ~(size_t)255; return o; };
    unsigned short* xp  = (unsigned short*)(ws + take((size_t)VC * 512 * 2));
    unsigned short* h1  = (unsigned short*)(ws + take((size_t)VC * 1024 * 2));
    unsigned short* h2  = (unsigned short*)(ws + take((size_t)VC * 1024 * 2));
    unsigned short* w1f = (unsigned short*)(ws + take(7 * 4 * 64 * 8 * 2));
    unsigned short* w2f = (unsigned short*)(ws + take(14 * 4 * 64 * 8 * 2));
    float* stats        = (float*)(ws + take(256 * 4));       // [sum1|sq1|sum2|sq2]
    float* params       = (float*)(ws + take(256 * 4));       // [sc1|sh1|sc2|sh2]

    // xt (bf16 transposed fine grid) lives in d_out as scratch (dead before final_out)
    unsigned short* xt = (unsigned short*)d_out;

    const float inv_n = 1.0f / (16.0f * (float)VC);
    const int nblk = (VC + 31) / 32;   // 32 verts per 512-thread conv block

    prep_w<<<32, 256, 0, stream>>>(w1, w2, w1f, w2f, stats);
    transpose_x<<<(VFINE + 63) / 64, 256, 0, stream>>>(x, xt, VFINE);
    pool_k<<<(VC + 3) / 4, 256, 0, stream>>>(xt, dn, xp, VC);
    conv_mfma<1><<<nblk, 512, 0, stream>>>(xp, cn, w1f, h1, stats, VC);
    bn_params<<<1, 64, 0, stream>>>(stats, g1, be1, params, inv_n);
    bn_apply<<<2048, 256, 0, stream>>>(h1, params, VC * 128);
    conv_mfma<2><<<nblk, 512, 0, stream>>>(h1, cn, w2f, h2, stats + 128, VC);
    bn_params<<<1, 64, 0, stream>>>(stats + 128, g2, be2, params + 128, inv_n);
    final_out<<<(VC + 63) / 64, 256, 0, stream>>>(h2, params + 128, out, VC);
}

// Round 9
// 480.385 us; speedup vs baseline: 1.2551x; 1.0949x over previous
//
#include <hip/hip_runtime.h>
#include <hip/hip_bf16.h>

// DownBlock: pool(mean over 7 down-neighbors) -> conv1(K=7, 32->64) -> BN+LReLU
//         -> conv2(K=7, 64->64) -> BN+LReLU
// B=16, C_IN=32, C=64, V_FINE=163842, V=40962, K=7.
// Biases b1/b2 are dead: BN's mean subtraction absorbs per-channel constants.
// Convs are pinned at the per-CU outstanding-miss limit (~4.4 TB/s gather);
// R5's simple form is optimal (R6/R7/R8 scheduling variants all regressed).
// R9 = exact R5 conv/pool + bn_params folded into bn_apply/final_out.

#define B_SZ     16
#define CIN      32
#define CMID     64
#define VFINE    163842
#define VC       40962
#define KNB      7

typedef __attribute__((ext_vector_type(8))) short  short8;   // 8 x bf16 (as i16)
typedef __attribute__((ext_vector_type(4))) float  f32x4;
typedef __attribute__((ext_vector_type(4))) unsigned short u16x4;

__device__ inline float bf2f(unsigned short u) {
    return __builtin_bit_cast(float, (unsigned int)(((unsigned int)u) << 16));
}
__device__ inline unsigned short f2bf(float f) {
    __hip_bfloat16 h = __float2bfloat16(f);
    return __builtin_bit_cast(unsigned short, h);
}

// ---------------------------------------------------------------------------
// Prep: reorder W into per-lane MFMA A-fragments, bf16. Also zeroes stats.
// Fragment (chunk, otile): lane l, elem j ->  A[o = otile*16 + (l&15)][kk = (l>>4)*8 + j]
// conv1: chunk cc = k (7 chunks), c = kk.        W1[o][c*7+k]
// conv2: chunk cc = k*2 + ch (14), c = ch*32+kk. W2[o][c*7+k]
// ---------------------------------------------------------------------------
__global__ void prep_w(const float* __restrict__ w1, const float* __restrict__ w2,
                       unsigned short* __restrict__ w1f, unsigned short* __restrict__ w2f,
                       float* __restrict__ stats) {
    int tid = blockIdx.x * blockDim.x + threadIdx.x;
    int stride = gridDim.x * blockDim.x;
    if (blockIdx.x == 0 && threadIdx.x < 256) stats[threadIdx.x] = 0.f;
    const int total1 = 7 * 4 * 64 * 8;
    for (int idx = tid; idx < total1; idx += stride) {
        int j = idx & 7, l = (idx >> 3) & 63, t = (idx >> 9) & 3, cc = idx >> 11;
        int o = t * 16 + (l & 15);
        int kk = (l >> 4) * 8 + j;
        w1f[idx] = f2bf(w1[o * 224 + kk * 7 + cc]);
    }
    const int total2 = 14 * 4 * 64 * 8;
    for (int idx = tid; idx < total2; idx += stride) {
        int j = idx & 7, l = (idx >> 3) & 63, t = (idx >> 9) & 3, cc = idx >> 11;
        int o = t * 16 + (l & 15);
        int kk = (l >> 4) * 8 + j;
        int k = cc >> 1, ch = cc & 1;
        int c = ch * 32 + kk;
        w2f[idx] = f2bf(w2[o * 448 + c * 7 + k]);
    }
}

// ---------------------------------------------------------------------------
// Transpose x (512 rows x VFINE) f32 -> xt[v][512] bf16.
// 64-vertex tile, two 256-channel phases. LDS [64 verts][258 u16] (33KB).
// ---------------------------------------------------------------------------
__global__ __launch_bounds__(256) void transpose_x(const float* __restrict__ x,
                                                   unsigned short* __restrict__ xt, int vf) {
    __shared__ __align__(16) unsigned short lds[64 * 258];
    const int t = threadIdx.x;
    const int v0 = blockIdx.x * 64;
    const int j  = t & 15;        // load phase: vert group (4 verts)
    const int r0 = t >> 4;        // load phase: row base
    const int lane = t & 63;
    const int wid = t >> 6;

#pragma unroll
    for (int p = 0; p < 2; ++p) {
        if (p) __syncthreads();
#pragma unroll
        for (int it = 0; it < 16; ++it) {
            int r = r0 + it * 16;          // row within phase 0..255
            int row = p * 256 + r;
            int vg = v0 + 4 * j;
            f32x4 d = {0.f, 0.f, 0.f, 0.f};
            if (vg + 3 < vf) {
                d = *reinterpret_cast<const f32x4*>(x + (size_t)row * vf + vg);
            } else {
#pragma unroll
                for (int q = 0; q < 4; ++q)
                    if (vg + q < vf) d[q] = x[(size_t)row * vf + vg + q];
            }
#pragma unroll
            for (int q = 0; q < 4; ++q)
                lds[(4 * j + q) * 258 + r] = f2bf(d[q]);
        }
        __syncthreads();
#pragma unroll
        for (int i = 0; i < 16; ++i) {
            int v = wid * 16 + i;
            u16x4 o = *reinterpret_cast<const u16x4*>(lds + v * 258 + 4 * lane);
            if (v0 + v < vf)
                *reinterpret_cast<u16x4*>(xt + (size_t)(v0 + v) * 512 + p * 256 + 4 * lane) = o;
        }
    }
}

// ---------------------------------------------------------------------------
// Pool: xp[v][b][c] = mean_k xt[dn[v][k]][b][c]. One wave per coarse vertex.
// (R5 form: in-loop index load; compiler pipelines it under prior work.)
// ---------------------------------------------------------------------------
__global__ __launch_bounds__(256) void pool_k(const unsigned short* __restrict__ xt,
                                              const int* __restrict__ dn,
                                              unsigned short* __restrict__ xp, int vc) {
    int wid = (blockIdx.x * blockDim.x + threadIdx.x) >> 6;
    int lane = threadIdx.x & 63;
    if (wid >= vc) return;
    float acc[8];
#pragma unroll
    for (int j = 0; j < 8; ++j) acc[j] = 0.f;
#pragma unroll
    for (int k = 0; k < 7; ++k) {
        int n = __builtin_amdgcn_readfirstlane(dn[(size_t)wid * 7 + k]);
        short8 d = *reinterpret_cast<const short8*>(xt + (size_t)n * 512 + lane * 8);
#pragma unroll
        for (int j = 0; j < 8; ++j) acc[j] += bf2f((unsigned short)d[j]);
    }
    short8 o;
#pragma unroll
    for (int j = 0; j < 8; ++j) o[j] = (short)f2bf(acc[j] * (1.f / 7.f));
    *reinterpret_cast<short8*>(xp + (size_t)wid * 512 + lane * 8) = o;
}

// ---------------------------------------------------------------------------
// Gathered conv via MFMA 16x16x32 bf16. 512-thread block = 8 waves;
// 4 verts/wave (block = 32 verts). Weights LDS-staged. In-loop neighbor
// index loads (R5-proven: compiler pipelines them). unroll 1.
// BN stats fused in epilogue. xin: [vc][16][32*CCH]; hout: [vc][16][64].
// ---------------------------------------------------------------------------
template <int CCH>
__global__ __launch_bounds__(512, 4) void conv_mfma(const unsigned short* __restrict__ xin,
                                                    const int* __restrict__ neigh,
                                                    const unsigned short* __restrict__ wfrag,
                                                    unsigned short* __restrict__ hout,
                                                    float* __restrict__ stats,
                                                    int vc) {
    constexpr int C = 32 * CCH;
    constexpr int NCHUNK = 7 * CCH;
    __shared__ __align__(16) unsigned short wlds[NCHUNK * 2048];
    __shared__ float bsum[128];
    for (int i = threadIdx.x; i < NCHUNK * 256; i += 512)
        reinterpret_cast<short8*>(wlds)[i] = reinterpret_cast<const short8*>(wfrag)[i];
    if (threadIdx.x < 128) bsum[threadIdx.x] = 0.f;
    __syncthreads();

    const int wid = threadIdx.x >> 6;
    const int lane = threadIdx.x & 63;
    const int lb = lane & 15, lg = lane >> 4;
    const int v0 = blockIdx.x * 32 + wid * 4;
    const int boff = lb * C + lg * 8;   // per-lane element offset within vertex block

    f32x4 acc[4][4];
#pragma unroll
    for (int i = 0; i < 4; ++i)
#pragma unroll
        for (int t = 0; t < 4; ++t) acc[i][t] = (f32x4){0.f, 0.f, 0.f, 0.f};

#pragma unroll 1
    for (int k = 0; k < 7; ++k) {
        int n[4];
#pragma unroll
        for (int i = 0; i < 4; ++i) {
            int v = v0 + i;
            n[i] = __builtin_amdgcn_readfirstlane((v < vc) ? neigh[(size_t)v * 7 + k] : 0);
        }
#pragma unroll
        for (int ch = 0; ch < CCH; ++ch) {
            const int chunk = k * CCH + ch;
            const short8* wp = reinterpret_cast<const short8*>(wlds) + (chunk * 4) * 64 + lane;
            const short8 a0 = wp[0];
            const short8 a1 = wp[64];
            const short8 a2 = wp[128];
            const short8 a3 = wp[192];
#pragma unroll
            for (int i = 0; i < 4; ++i) {
                const short8 b = *reinterpret_cast<const short8*>(
                    xin + (size_t)n[i] * (16 * C) + boff + ch * 32);
                acc[i][0] = __builtin_amdgcn_mfma_f32_16x16x32_bf16(a0, b, acc[i][0], 0, 0, 0);
                acc[i][1] = __builtin_amdgcn_mfma_f32_16x16x32_bf16(a1, b, acc[i][1], 0, 0, 0);
                acc[i][2] = __builtin_amdgcn_mfma_f32_16x16x32_bf16(a2, b, acc[i][2], 0, 0, 0);
                acc[i][3] = __builtin_amdgcn_mfma_f32_16x16x32_bf16(a3, b, acc[i][3], 0, 0, 0);
            }
        }
    }

    // epilogue: D[o][b], o = t*16 + lg*4 + r, b = lb. Stats live only here.
    float ssum[16], ssq[16];
#pragma unroll
    for (int i = 0; i < 16; ++i) { ssum[i] = 0.f; ssq[i] = 0.f; }
#pragma unroll
    for (int i = 0; i < 4; ++i) {
        const int v = v0 + i;
        if (v < vc) {
#pragma unroll
            for (int t = 0; t < 4; ++t) {
                u16x4 st;
#pragma unroll
                for (int r = 0; r < 4; ++r) {
                    float f = acc[i][t][r];
                    ssum[t * 4 + r] += f;
                    ssq[t * 4 + r] += f * f;
                    st[r] = f2bf(f);
                }
                *reinterpret_cast<u16x4*>(hout + (size_t)v * 1024 + lb * 64 + t * 16 + lg * 4) = st;
            }
        }
    }
    // reduce over the 16 batch lanes
#pragma unroll
    for (int m = 1; m <= 8; m <<= 1) {
#pragma unroll
        for (int i = 0; i < 16; ++i) {
            ssum[i] += __shfl_xor(ssum[i], m, 64);
            ssq[i] += __shfl_xor(ssq[i], m, 64);
        }
    }
    if (lb == 0) {
#pragma unroll
        for (int t = 0; t < 4; ++t)
#pragma unroll
            for (int r = 0; r < 4; ++r) {
                int o = t * 16 + lg * 4 + r;
                atomicAdd(&bsum[o], ssum[t * 4 + r]);
                atomicAdd(&bsum[64 + o], ssq[t * 4 + r]);
            }
    }
    __syncthreads();
    if (threadIdx.x < 128) atomicAdd(&stats[threadIdx.x], bsum[threadIdx.x]);
}

// ---------------------------------------------------------------------------
// BN+LReLU apply in-place on h ([v][b][64] bf16). BN params computed per
// block from stats/gamma/beta (folds the former bn_params launch).
// ---------------------------------------------------------------------------
__global__ __launch_bounds__(256) void bn_apply(unsigned short* __restrict__ h,
                                                const float* __restrict__ stats,
                                                const float* __restrict__ gamma,
                                                const float* __restrict__ beta,
                                                float inv_n, int total8) {
    int stride = gridDim.x * blockDim.x;
    int idx0 = blockIdx.x * blockDim.x + threadIdx.x;
    int c0 = (idx0 & 7) * 8;
    float sc[8], sh[8];
#pragma unroll
    for (int j = 0; j < 8; ++j) {
        int c = c0 + j;
        float mean = stats[c] * inv_n;
        float var = stats[64 + c] * inv_n - mean * mean;
        float s = gamma[c] * rsqrtf(var + 1e-5f);
        sc[j] = s;
        sh[j] = beta[c] - mean * s;
    }
    for (int idx = idx0; idx < total8; idx += stride) {
        short8 d = *reinterpret_cast<const short8*>(h + (size_t)idx * 8);
        short8 o;
#pragma unroll
        for (int j = 0; j < 8; ++j) {
            float y = sc[j] * bf2f((unsigned short)d[j]) + sh[j];
            y = fmaxf(y, 0.2f * y);
            o[j] = (short)f2bf(y);
        }
        *reinterpret_cast<short8*>(h + (size_t)idx * 8) = o;
    }
}

// ---------------------------------------------------------------------------
// Final: BN2+LReLU on h2[v][b][o] bf16, transpose -> out[b][o][v] f32 via LDS.
// BN2 params computed per block from stats2/gamma2/beta2 (folded launch).
// ---------------------------------------------------------------------------
__global__ __launch_bounds__(256) void final_out(const unsigned short* __restrict__ h2,
                                                 const float* __restrict__ stats,
                                                 const float* __restrict__ gamma,
                                                 const float* __restrict__ beta,
                                                 float inv_n,
                                                 float* __restrict__ out, int vc) {
    __shared__ float lds[128 * 65];
    const int t = threadIdx.x;
    const int v0 = blockIdx.x * 64;
    const int sub = t & 15, vloc = t >> 4;
    const int o0 = (sub & 7) * 8;
    float sc[8], sh[8];
#pragma unroll
    for (int j = 0; j < 8; ++j) {
        int c = o0 + j;
        float mean = stats[c] * inv_n;
        float var = stats[64 + c] * inv_n - mean * mean;
        float s = gamma[c] * rsqrtf(var + 1e-5f);
        sc[j] = s;
        sh[j] = beta[c] - mean * s;
    }
    for (int c = 0; c < 8; ++c) {
        if (c) __syncthreads();
#pragma unroll
        for (int i = 0; i < 4; ++i) {
            int v = v0 + vloc + 16 * i;
            short8 d = {0, 0, 0, 0, 0, 0, 0, 0};
            if (v < vc)
                d = *reinterpret_cast<const short8*>(h2 + (size_t)v * 1024 + c * 128 + sub * 8);
#pragma unroll
            for (int j = 0; j < 8; ++j) {
                float y = sc[j] * bf2f((unsigned short)d[j]) + sh[j];
                y = fmaxf(y, 0.2f * y);
                lds[(sub * 8 + j) * 65 + vloc + 16 * i] = y;
            }
        }
        __syncthreads();
#pragma unroll
        for (int q = 0; q < 8; ++q) {
            int idx = t + 256 * q;       // 0..2047
            int r = idx >> 4;            // 0..127
            int vq = (idx & 15) * 4;
            int v = v0 + vq;
            const float* lp = lds + r * 65 + vq;
            if (v + 3 < vc) {
                f32x4 o = {lp[0], lp[1], lp[2], lp[3]};
                *reinterpret_cast<f32x4*>(out + (size_t)(c * 128 + r) * vc + v) = o;
            } else {
#pragma unroll
                for (int e = 0; e < 4; ++e)
                    if (v + e < vc) out[(size_t)(c * 128 + r) * vc + v + e] = lp[e];
            }
        }
    }
}

// ---------------------------------------------------------------------------
extern "C" void kernel_launch(void* const* d_in, const int* in_sizes, int n_in,
                              void* d_out, int out_size, void* d_ws, size_t ws_size,
                              hipStream_t stream) {
    const float* x   = (const float*)d_in[0];
    const float* w1  = (const float*)d_in[1];
    const float* g1  = (const float*)d_in[3];
    const float* be1 = (const float*)d_in[4];
    const float* w2  = (const float*)d_in[5];
    const float* g2  = (const float*)d_in[7];
    const float* be2 = (const float*)d_in[8];
    const int* cn    = (const int*)d_in[9];
    const int* dn    = (const int*)d_in[10];
    float* out = (float*)d_out;

    // workspace layout (~210 MB)
    char* ws = (char*)d_ws;
    size_t off = 0;
    auto take = [&](size_t bytes) { size_t o = off; off = (off + bytes + 255) & ~(size_t)255; return o; };
    unsigned short* xp  = (unsigned short*)(ws + take((size_t)VC * 512 * 2));
    unsigned short* h1  = (unsigned short*)(ws + take((size_t)VC * 1024 * 2));
    unsigned short* h2  = (unsigned short*)(ws + take((size_t)VC * 1024 * 2));
    unsigned short* w1f = (unsigned short*)(ws + take(7 * 4 * 64 * 8 * 2));
    unsigned short* w2f = (unsigned short*)(ws + take(14 * 4 * 64 * 8 * 2));
    float* stats        = (float*)(ws + take(256 * 4));       // [sum1|sq1|sum2|sq2]

    // xt (bf16 transposed fine grid) lives in d_out as scratch (dead before final_out)
    unsigned short* xt = (unsigned short*)d_out;

    const float inv_n = 1.0f / (16.0f * (float)VC);
    const int nblk = (VC + 31) / 32;   // 32 verts per 512-thread conv block

    prep_w<<<32, 256, 0, stream>>>(w1, w2, w1f, w2f, stats);
    transpose_x<<<(VFINE + 63) / 64, 256, 0, stream>>>(x, xt, VFINE);
    pool_k<<<(VC + 3) / 4, 256, 0, stream>>>(xt, dn, xp, VC);
    conv_mfma<1><<<nblk, 512, 0, stream>>>(xp, cn, w1f, h1, stats, VC);
    bn_apply<<<2048, 256, 0, stream>>>(h1, stats, g1, be1, inv_n, VC * 128);
    conv_mfma<2><<<nblk, 512, 0, stream>>>(h1, cn, w2f, h2, stats + 128, VC);
    final_out<<<(VC + 63) / 64, 256, 0, stream>>>(h2, stats + 128, g2, be2, inv_n, out, VC);
}